// Round 13
// baseline (643.797 us; speedup 1.0000x reference)
//
#include <hip/hip_runtime.h>
#include <hip/hip_bf16.h>
#include <hip/hip_cooperative_groups.h>

namespace cg = cooperative_groups;

#define N_NODES 50000
#define NREL 16
#define HID 64
#define NCLS 16
#define NBKT (N_NODES * NREL)       // 800000 buckets (dst*16 + rel)
#define SB 2048                     // scan elems per block
#define NSB ((NBKT + SB - 1) / SB)  // 391
#define TILE 32                     // dst nodes per tile
#define NTB ((N_NODES + TILE - 1) / TILE)  // 1563
#define PGRID 256                   // persistent blocks for fuse1 (1/CU)
#define COOPG 1024                  // cooperative pre-kernel blocks (4/CU)
#define XCHUNKS (N_NODES * HID / 8)        // 400000
#define W1N (17 * HID * HID)               // 69632
#define W2N (17 * NCLS * HID)              // 17408

typedef __attribute__((ext_vector_type(8))) short bf16x8;
typedef __attribute__((ext_vector_type(4))) float f32x4;
typedef __attribute__((ext_vector_type(2))) int i32x2;

static __device__ __forceinline__ unsigned short f2bf(float f) {
    __hip_bfloat16 h = __float2bfloat16(f);
    return *reinterpret_cast<unsigned short*>(&h);
}
static __device__ __forceinline__ float bf2f(unsigned short u) {
    __hip_bfloat16 h;
    *reinterpret_cast<unsigned short*>(&h) = u;
    return __bfloat162float(h);
}

#define MFMA16(A, B, C) __builtin_amdgcn_mfma_f32_16x16x32_bf16((A), (B), (C), 0, 0, 0)

// Inline-asm loads: cannot be sunk/split by the compiler; results valid only
// after VWAIT0 (s_waitcnt vmcnt(0) + sched_barrier per rule #18).
#define LD128A(D, P) \
    asm volatile("global_load_dwordx4 %0, %1, off" : "=v"(D) : "v"((const void*)(P)) : "memory")
#define LD64A(D, P) \
    asm volatile("global_load_dwordx2 %0, %1, off" : "=v"(D) : "v"((const void*)(P)) : "memory")
#define VWAIT0()                                           \
    do {                                                   \
        asm volatile("s_waitcnt vmcnt(0)" ::: "memory");   \
        __builtin_amdgcn_sched_barrier(0);                 \
    } while (0)

// ---------------------------------------------------------------------------
// ws layout (R6-proven):
//   bcnt/rstart i32[800020] | rank i32[E] | bsum i32[512]
//   | sedge int2[E] {src | rel<<16, inv} | WbT1 | WbT2 | xb | X1b
// Pre-pipeline: ONE cooperative kernel (zero -> hist+rank+cvt -> scan1 ->
// scan23 -> scat with grid.sync between phases) — identical work to the
// R6 chain, zero inter-phase launch overhead. Fallback to the R6 5-kernel
// chain if cooperative launch is rejected (e.g. by graph capture).
// fuse1 = R10's persistent asm-pipelined kernel (57 us, frozen).
// fuse2 = R6's 256-thread kernel (frozen).
// ---------------------------------------------------------------------------

// Cooperative all-in-one pre-processing kernel.
__global__ __launch_bounds__(256) void coop_pre_k(
        const int* __restrict__ srcp, const int* __restrict__ dstp,
        const int* __restrict__ et, int* __restrict__ bcnt,
        int* __restrict__ rank, int E,
        const float* __restrict__ x, const float* __restrict__ W1,
        const float* __restrict__ root1, const float* __restrict__ W2,
        const float* __restrict__ root2, ushort* __restrict__ xb,
        ushort* __restrict__ WbT1, ushort* __restrict__ WbT2,
        int* __restrict__ bsum, int2* __restrict__ sedge) {
    __shared__ int ts[256];
    __shared__ int ws[4];
    int tid = threadIdx.x, bid = blockIdx.x;
    int gsz = gridDim.x * 256;
    int gtid = bid * 256 + tid;

    // phase 0: zero bucket counters
    for (int i = gtid; i < NBKT + 20; i += gsz) bcnt[i] = 0;
    cg::this_grid().sync();

    // phase 1a: histogram + per-edge rank
    for (int i = gtid; i < E; i += gsz) {
        int b = dstp[i] * NREL + et[i];
        rank[i] = atomicAdd(&bcnt[b], 1);
    }
    // phase 1b: cvt x -> bf16, transposed bf16 weights
    for (int i = gtid; i < XCHUNKS + W1N + W2N; i += gsz) {
        if (i < XCHUNKS) {
            float4 f0 = *(const float4*)(x + (size_t)i * 8);
            float4 f1 = *(const float4*)(x + (size_t)i * 8 + 4);
            bf16x8 o;
            o[0] = (short)f2bf(f0.x); o[1] = (short)f2bf(f0.y);
            o[2] = (short)f2bf(f0.z); o[3] = (short)f2bf(f0.w);
            o[4] = (short)f2bf(f1.x); o[5] = (short)f2bf(f1.y);
            o[6] = (short)f2bf(f1.z); o[7] = (short)f2bf(f1.w);
            *(bf16x8*)(xb + (size_t)i * 8) = o;
        } else {
            int j = i - XCHUNKS;
            if (j < W1N) {
                int t = j >> 12, rem = j & 4095, n = rem >> 6, k = rem & 63;
                float v = (t < 16) ? W1[(size_t)t * HID * HID + k * HID + n]
                                   : root1[k * HID + n];
                WbT1[j] = f2bf(v);
            } else {
                int m = j - W1N;
                int t = m >> 10, rem = m & 1023, n = rem >> 6, k = rem & 63;
                float v = (t < 16) ? W2[(size_t)t * HID * NCLS + k * NCLS + n]
                                   : root2[k * NCLS + n];
                WbT2[m] = f2bf(v);
            }
        }
    }
    cg::this_grid().sync();

    // phase 2: per-chunk sums (scan1)
    for (int c = bid; c < NSB; c += gridDim.x) {
        int base = c * SB + tid * 8;
        int s = 0;
#pragma unroll
        for (int j = 0; j < 8; ++j)
            if (base + j < NBKT) s += bcnt[base + j];
#pragma unroll
        for (int off = 1; off < 64; off <<= 1) s += __shfl_xor(s, off, 64);
        if ((tid & 63) == 0) ws[tid >> 6] = s;
        __syncthreads();
        if (tid == 0) bsum[c] = ws[0] + ws[1] + ws[2] + ws[3];
        __syncthreads();
    }
    cg::this_grid().sync();

    // phase 3: cross-chunk prefix + per-chunk exclusive scan IN PLACE (scan23)
    for (int c = bid; c < NSB; c += gridDim.x) {
        int ps = 0;
        for (int j = tid; j < c; j += 256) ps += bsum[j];
#pragma unroll
        for (int off = 1; off < 64; off <<= 1) ps += __shfl_xor(ps, off, 64);
        if ((tid & 63) == 0) ws[tid >> 6] = ps;
        __syncthreads();
        int prefix = ws[0] + ws[1] + ws[2] + ws[3];

        int base = c * SB + tid * 8;
        int a[8];
        int s = 0;
#pragma unroll
        for (int j = 0; j < 8; ++j) {
            a[j] = (base + j < NBKT) ? bcnt[base + j] : 0;
            s += a[j];
        }
        ts[tid] = s;
        __syncthreads();
        int acc = s;
        for (int off = 1; off < 256; off <<= 1) {
            int u = (tid >= off) ? ts[tid - off] : 0;
            __syncthreads();
            acc += u;
            ts[tid] = acc;
            __syncthreads();
        }
        int run = prefix + (acc - s);
#pragma unroll
        for (int j = 0; j < 8; ++j) {
            if (base + j < NBKT) bcnt[base + j] = run;
            run += a[j];
        }
        __syncthreads();
    }
    if (gtid == 0) bcnt[NBKT] = E;
    cg::this_grid().sync();

    // phase 4: rank-ordered scatter with premultiplied mean weight
    for (int i = gtid; i < E; i += gsz) {
        int r = et[i];
        int b = dstp[i] * NREL + r;
        int lo = bcnt[b], hi = bcnt[b + 1];
        float inv = 1.0f / (float)(hi - lo);
        sedge[lo + rank[i]] = make_int2(srcp[i] | (r << 16), __float_as_int(inv));
    }
}

// --------------------- fallback pre-pipeline (R6-proven) -------------------

__global__ __launch_bounds__(256) void pre_k(const int* __restrict__ dstp,
                                             const int* __restrict__ et,
                                             int* __restrict__ bcnt,
                                             int* __restrict__ rank, int E,
                                             const float* __restrict__ x,
                                             const float* __restrict__ W1,
                                             const float* __restrict__ root1,
                                             const float* __restrict__ W2,
                                             const float* __restrict__ root2,
                                             ushort* __restrict__ xb,
                                             ushort* __restrict__ WbT1,
                                             ushort* __restrict__ WbT2) {
    int eb = (E + 255) >> 8;
    if ((int)blockIdx.x < eb) {
        int i = blockIdx.x * 256 + threadIdx.x;
        if (i < E) {
            int b = dstp[i] * NREL + et[i];
            rank[i] = atomicAdd(&bcnt[b], 1);
        }
        return;
    }
    int i = (blockIdx.x - eb) * 256 + threadIdx.x;
    if (i < XCHUNKS) {
        float4 f0 = *(const float4*)(x + (size_t)i * 8);
        float4 f1 = *(const float4*)(x + (size_t)i * 8 + 4);
        bf16x8 o;
        o[0] = (short)f2bf(f0.x); o[1] = (short)f2bf(f0.y);
        o[2] = (short)f2bf(f0.z); o[3] = (short)f2bf(f0.w);
        o[4] = (short)f2bf(f1.x); o[5] = (short)f2bf(f1.y);
        o[6] = (short)f2bf(f1.z); o[7] = (short)f2bf(f1.w);
        *(bf16x8*)(xb + (size_t)i * 8) = o;
    } else {
        int j = i - XCHUNKS;
        if (j < W1N) {
            int t = j >> 12, rem = j & 4095, n = rem >> 6, k = rem & 63;
            float v = (t < 16) ? W1[(size_t)t * HID * HID + k * HID + n]
                               : root1[k * HID + n];
            WbT1[j] = f2bf(v);
        } else {
            int m = j - W1N;
            if (m < W2N) {
                int t = m >> 10, rem = m & 1023, n = rem >> 6, k = rem & 63;
                float v = (t < 16) ? W2[(size_t)t * HID * NCLS + k * NCLS + n]
                                   : root2[k * NCLS + n];
                WbT2[m] = f2bf(v);
            }
        }
    }
}

__global__ __launch_bounds__(256) void scan1_k(const int* __restrict__ bcnt,
                                               int* __restrict__ bsum) {
    int b = blockIdx.x, t = threadIdx.x;
    int base = b * SB + t * 8;
    int s = 0;
#pragma unroll
    for (int j = 0; j < 8; ++j)
        if (base + j < NBKT) s += bcnt[base + j];
#pragma unroll
    for (int off = 1; off < 64; off <<= 1) s += __shfl_xor(s, off, 64);
    __shared__ int ws[4];
    if ((t & 63) == 0) ws[t >> 6] = s;
    __syncthreads();
    if (t == 0) bsum[b] = ws[0] + ws[1] + ws[2] + ws[3];
}

__global__ __launch_bounds__(512) void scan2_k(int* __restrict__ bsum,
                                               int* __restrict__ rstart, int E) {
    __shared__ int ts[512];
    int t = threadIdx.x;
    int v = (t < NSB) ? bsum[t] : 0;
    ts[t] = v;
    __syncthreads();
    int acc = v;
    for (int off = 1; off < 512; off <<= 1) {
        int u = (t >= off) ? ts[t - off] : 0;
        __syncthreads();
        acc += u;
        ts[t] = acc;
        __syncthreads();
    }
    if (t < NSB) bsum[t] = acc - v;
    if (t == 0) rstart[NBKT] = E;
}

__global__ __launch_bounds__(256) void scan3_k(int* __restrict__ bcnt,
                                               const int* __restrict__ bsum) {
    int b = blockIdx.x, t = threadIdx.x;
    int base = b * SB + t * 8;
    int a[8];
    int s = 0;
#pragma unroll
    for (int j = 0; j < 8; ++j) {
        a[j] = (base + j < NBKT) ? bcnt[base + j] : 0;
        s += a[j];
    }
    __shared__ int ts[256];
    ts[t] = s;
    __syncthreads();
    int acc = s;
    for (int off = 1; off < 256; off <<= 1) {
        int u = (t >= off) ? ts[t - off] : 0;
        __syncthreads();
        acc += u;
        ts[t] = acc;
        __syncthreads();
    }
    int run = bsum[b] + (acc - s);
#pragma unroll
    for (int j = 0; j < 8; ++j) {
        if (base + j < NBKT) bcnt[base + j] = run;
        run += a[j];
    }
}

__global__ __launch_bounds__(256) void scat_k(const int* __restrict__ srcp,
                                              const int* __restrict__ dstp,
                                              const int* __restrict__ et,
                                              const int* __restrict__ rank,
                                              const int* __restrict__ rstart,
                                              int2* __restrict__ sedge, int E) {
    int i = blockIdx.x * 256 + threadIdx.x;
    if (i < E) {
        int r = et[i];
        int b = dstp[i] * NREL + r;
        int lo = rstart[b], hi = rstart[b + 1];
        float inv = 1.0f / (float)(hi - lo);
        sedge[lo + rank[i]] = make_int2(srcp[i] | (r << 16), __float_as_int(inv));
    }
}

// ---------------------------------------------------------------------------
// fuse1 gather building blocks (R10): 64 groups = 32 nodes x 2 rel-halves.
// Ab row layout: [16 rel][32 node][128 B], XOR-swizzled byte^=((node&7)<<4).
// ---------------------------------------------------------------------------

#define RSTART_LOAD(T, LO, HI)                                                \
    do {                                                                      \
        int node_ = (T) * TILE + g;                                           \
        LO = 0; HI = 0;                                                       \
        if (node_ < N_NODES) {                                                \
            int b0_ = node_ * NREL + h * 8;                                   \
            LO = rstart[b0_];                                                 \
            HI = rstart[b0_ + 8];                                             \
        }                                                                     \
    } while (0)

#define DESC_ISSUE(LO, HI)                                                    \
    do {                                                                      \
        int dg_ = (HI) - (LO);                                                \
        int bs_ = dg_ > 0 ? (LO) : 0;                                         \
        int lt_ = dg_ > 0 ? (HI)-1 : 0;                                       \
        _Pragma("unroll") for (int j_ = 0; j_ < 16; ++j_) {                   \
            int ix_ = bs_ + j_;                                               \
            if (ix_ > lt_) ix_ = lt_;                                         \
            LD64A(d[j_], sedge + ix_);                                        \
        }                                                                     \
    } while (0)

#define FEAT_ISSUE()                                                          \
    do {                                                                      \
        _Pragma("unroll") for (int j_ = 0; j_ < 16; ++j_)                     \
            LD128A(v[j_], xcol + (size_t)(d[j_].x & 0xFFFF) * HID);           \
    } while (0)

#define GFLUSHX(ABP)                                                          \
    {                                                                         \
        bf16x8 o_;                                                            \
        o_[0] = (short)f2bf(acc_[0]); o_[1] = (short)f2bf(acc_[1]);           \
        o_[2] = (short)f2bf(acc_[2]); o_[3] = (short)f2bf(acc_[3]);           \
        o_[4] = (short)f2bf(acc_[4]); o_[5] = (short)f2bf(acc_[5]);           \
        o_[6] = (short)f2bf(acc_[6]); o_[7] = (short)f2bf(acc_[7]);           \
        *(bf16x8*)((ABP) + ((curRel_ * (TILE * 128) + rowoff) ^ swg)) = o_;   \
        acc_[0] = 0.f; acc_[1] = 0.f; acc_[2] = 0.f; acc_[3] = 0.f;           \
        acc_[4] = 0.f; acc_[5] = 0.f; acc_[6] = 0.f; acc_[7] = 0.f;           \
    }

#define CONSUME(ABP, LO, HI)                                                  \
    do {                                                                      \
        char* abp_ = (char*)(ABP);                                            \
        int deg_ = (HI) - (LO);                                               \
        const bf16x8 zz_ = {0, 0, 0, 0, 0, 0, 0, 0};                          \
        _Pragma("unroll") for (int r_ = 0; r_ < 8; ++r_)                      \
            *(bf16x8*)(abp_ + (((h * 8 + r_) * (TILE * 128) + rowoff) ^ swg)) = zz_; \
        float acc_[8] = {0.f, 0.f, 0.f, 0.f, 0.f, 0.f, 0.f, 0.f};             \
        int curRel_ = h * 8;                                                  \
        _Pragma("unroll") for (int j_ = 0; j_ < 16; ++j_) {                   \
            if (j_ < deg_) {                                                  \
                int rr_ = (d[j_].x >> 16) & 15;                               \
                if (rr_ != curRel_) { GFLUSHX(abp_); curRel_ = rr_; }         \
                float iv_ = __int_as_float(d[j_].y);                          \
                _Pragma("unroll") for (int q_ = 0; q_ < 8; ++q_)              \
                    acc_[q_] = fmaf(iv_, bf2f((unsigned short)v[j_][q_]), acc_[q_]); \
            }                                                                 \
        }                                                                     \
        for (int e_ = (LO) + 16; e_ < (HI); ++e_) { /* rare tail */           \
            int2 m_ = sedge[e_];                                              \
            int rr_ = (m_.x >> 16) & 15;                                      \
            if (rr_ != curRel_) { GFLUSHX(abp_); curRel_ = rr_; }             \
            float iv_ = __int_as_float(m_.y);                                 \
            bf16x8 vv_ = *(const bf16x8*)(xcol + (size_t)(m_.x & 0xFFFF) * HID); \
            _Pragma("unroll") for (int q_ = 0; q_ < 8; ++q_)                  \
                acc_[q_] = fmaf(iv_, bf2f((unsigned short)vv_[q_]), acc_[q_]); \
        }                                                                     \
        if (deg_ > 0) GFLUSHX(abp_);                                          \
    } while (0)

__global__ __launch_bounds__(512, 2) void fuse1_k(const ushort* __restrict__ xb,
                                                  const int2* __restrict__ sedge,
                                                  const int* __restrict__ rstart,
                                                  const ushort* __restrict__ WbT1,
                                                  const float* __restrict__ b1,
                                                  ushort* __restrict__ X1b) {
    __shared__ bf16x8 Abuf[2][NREL * TILE * 8];  // 131072 B
    __shared__ float P[4][TILE][16];             // 8192 B
    int tid = threadIdx.x, bid = blockIdx.x;
    int wave = tid >> 6, lane = tid & 63;
    int mr = lane & 15, kq = lane >> 4;
    int cg_ = wave & 3, th = wave >> 2;  // col-group, task-half
    int grp = tid >> 3, l8 = tid & 7;
    int g = grp & 31, h = grp >> 5;
    int swg = (g & 7) << 4;
    int rowoff = (g << 7) + (l8 << 4);
    const ushort* xcol = xb + l8 * 8;
    int sw = (mr & 7) << 4;
    int a00o = ((mr << 7) + (kq << 4)) ^ sw;
    int a01o = ((mr << 7) + 64 + (kq << 4)) ^ sw;
    int a10o = (((16 + mr) << 7) + (kq << 4)) ^ sw;
    int a11o = (((16 + mr) << 7) + 64 + (kq << 4)) ^ sw;

    // weights in registers: this wave's 8 tasks (th*8+i) + root (t=16)
    const ushort* wbase = WbT1 + (cg_ * 16 + mr) * HID + kq * 8;
    bf16x8 w0[8], w1[8];
#pragma unroll
    for (int i = 0; i < 8; ++i) {
        w0[i] = *(const bf16x8*)(wbase + (th * 8 + i) * 4096);
        w1[i] = *(const bf16x8*)(wbase + (th * 8 + i) * 4096 + 32);
    }
    bf16x8 wr0 = *(const bf16x8*)(wbase + 16 * 4096);
    bf16x8 wr1 = *(const bf16x8*)(wbase + 16 * 4096 + 32);
    float4 bv = *(const float4*)(b1 + ((tid * 4) & 63));

    i32x2 d[16];
    bf16x8 v[16];

    // prologue: gather tile `bid` into Abuf[0]
    int lo, hi;
    RSTART_LOAD(bid, lo, hi);
    DESC_ISSUE(lo, hi);
    VWAIT0();
    FEAT_ISSUE();
    VWAIT0();
    CONSUME(&Abuf[0][0], lo, hi);
    int cur = 0;

    for (int k = 0;; ++k) {
        int tile = bid + k * PGRID;
        int dst0 = tile * TILE;
        bool hasNext = (tile + PGRID) < NTB;
        int nlo = 0, nhi = 0;
        if (hasNext) RSTART_LOAD(tile + PGRID, nlo, nhi);
        __syncthreads();  // Abuf[cur] visible to all
        if (hasNext) DESC_ISSUE(nlo, nhi);
        // root A-frags for this tile (asm; clamped rows)
        int r0 = dst0 + mr;      if (r0 >= N_NODES) r0 = N_NODES - 1;
        int r1 = dst0 + 16 + mr; if (r1 >= N_NODES) r1 = N_NODES - 1;
        bf16x8 ra00, ra01, ra10, ra11;
        LD128A(ra00, xb + (size_t)r0 * HID + kq * 8);
        LD128A(ra01, xb + (size_t)r0 * HID + kq * 8 + 32);
        LD128A(ra10, xb + (size_t)r1 * HID + kq * 8);
        LD128A(ra11, xb + (size_t)r1 * HID + kq * 8 + 32);

        const char* Abase = (const char*)&Abuf[cur][0] + th * (8 * TILE * 128);
        f32x4 c0 = {0.f, 0.f, 0.f, 0.f}, c1 = {0.f, 0.f, 0.f, 0.f};
#pragma unroll
        for (int i = 0; i < 4; ++i) {  // first half: desc latency hides here
            const char* At = Abase + i * (TILE * 128);
            bf16x8 a00 = *(const bf16x8*)(At + a00o);
            bf16x8 a01 = *(const bf16x8*)(At + a01o);
            bf16x8 a10 = *(const bf16x8*)(At + a10o);
            bf16x8 a11 = *(const bf16x8*)(At + a11o);
            c0 = MFMA16(a00, w0[i], c0);
            c0 = MFMA16(a01, w1[i], c0);
            c1 = MFMA16(a10, w0[i], c1);
            c1 = MFMA16(a11, w1[i], c1);
        }
        VWAIT0();  // desc + root ready
        if (hasNext) FEAT_ISSUE();  // feature latency hides under half 2
#pragma unroll
        for (int i = 4; i < 8; ++i) {
            const char* At = Abase + i * (TILE * 128);
            bf16x8 a00 = *(const bf16x8*)(At + a00o);
            bf16x8 a01 = *(const bf16x8*)(At + a01o);
            bf16x8 a10 = *(const bf16x8*)(At + a10o);
            bf16x8 a11 = *(const bf16x8*)(At + a11o);
            c0 = MFMA16(a00, w0[i], c0);
            c0 = MFMA16(a01, w1[i], c0);
            c1 = MFMA16(a10, w0[i], c1);
            c1 = MFMA16(a11, w1[i], c1);
        }
        if (th) {  // root task
            c0 = MFMA16(ra00, wr0, c0);
            c0 = MFMA16(ra01, wr1, c0);
            c1 = MFMA16(ra10, wr0, c1);
            c1 = MFMA16(ra11, wr1, c1);
        }
        // cross-half reduce in LDS P
        if (th == 0) {
#pragma unroll
            for (int j = 0; j < 4; ++j) {
                P[cg_][kq * 4 + j][mr] = c0[j];
                P[cg_][16 + kq * 4 + j][mr] = c1[j];
            }
        }
        __syncthreads();
        if (th == 1) {
#pragma unroll
            for (int j = 0; j < 4; ++j) {
                P[cg_][kq * 4 + j][mr] += c0[j];
                P[cg_][16 + kq * 4 + j][mr] += c1[j];
            }
        }
        __syncthreads();
        {
            int idx = tid * 4, row = idx >> 6, colb = idx & 63;
            int node = dst0 + row;
            if (node < N_NODES) {
                f32x4 pv = *(const f32x4*)&P[colb >> 4][row][colb & 15];
                ushort4 o;
                o.x = f2bf(fmaxf(pv[0] + bv.x, 0.f));
                o.y = f2bf(fmaxf(pv[1] + bv.y, 0.f));
                o.z = f2bf(fmaxf(pv[2] + bv.z, 0.f));
                o.w = f2bf(fmaxf(pv[3] + bv.w, 0.f));
                *(ushort4*)(X1b + (size_t)node * HID + colb) = o;
            }
        }
        if (!hasNext) break;
        VWAIT0();  // features ready
        CONSUME(&Abuf[cur ^ 1][0], nlo, nhi);
        cur ^= 1;
    }
}

// ---------------------------------------------------------------------------
// fuse2: R6's proven 256-thread kernel (32-deep clamped branchless gather).
// ---------------------------------------------------------------------------

#define GFLUSH()                                                              \
    {                                                                         \
        bf16x8 o_;                                                            \
        o_[0] = (short)f2bf(acc[0]); o_[1] = (short)f2bf(acc[1]);             \
        o_[2] = (short)f2bf(acc[2]); o_[3] = (short)f2bf(acc[3]);             \
        o_[4] = (short)f2bf(acc[4]); o_[5] = (short)f2bf(acc[5]);             \
        o_[6] = (short)f2bf(acc[6]); o_[7] = (short)f2bf(acc[7]);             \
        *(bf16x8*)(Ab + ((curRel * (TILE * 128) + rowoff) ^ sw)) = o_;        \
        acc[0] = 0.f; acc[1] = 0.f; acc[2] = 0.f; acc[3] = 0.f;               \
        acc[4] = 0.f; acc[5] = 0.f; acc[6] = 0.f; acc[7] = 0.f;               \
    }

static __device__ __forceinline__ void gather_tile(char* Ab,
                                                   const ushort* __restrict__ ft,
                                                   const int2* __restrict__ sedge,
                                                   const int* __restrict__ rstart,
                                                   int dst0, int tid) {
    int g = tid >> 3, l8 = tid & 7;
    int node = dst0 + g;
    bool valid = node < N_NODES;

    int lo = 0, hi = 0;
    if (valid) {
        lo = rstart[node * NREL];
        hi = rstart[node * NREL + NREL];
    }
    int deg = hi - lo;
    int base = (deg > 0) ? lo : 0;
    int last = (deg > 0) ? hi - 1 : 0;

    int sw = (g & 7) << 4;
    int rowoff = (g << 7) + (l8 << 4);
    const bf16x8 zz = {0, 0, 0, 0, 0, 0, 0, 0};

    int2 d[32];
#pragma unroll
    for (int j = 0; j < 32; ++j) {
        int idx = base + j;
        if (idx > last) idx = last;
        d[j] = sedge[idx];
    }

#pragma unroll
    for (int t = 0; t < 16; ++t)
        *(bf16x8*)(Ab + ((t * (TILE * 128) + rowoff) ^ sw)) = zz;
    {
        bf16x8 v = zz;
        if (valid) v = *(const bf16x8*)(ft + (size_t)node * HID + l8 * 8);
        *(bf16x8*)(Ab + ((16 * (TILE * 128) + rowoff) ^ sw)) = v;
    }

    const ushort* xcol = ft + l8 * 8;
    bf16x8 v[32];
#pragma unroll
    for (int j = 0; j < 32; ++j)
        v[j] = *(const bf16x8*)(xcol + (size_t)(d[j].x & 0xFFFF) * HID);
    __builtin_amdgcn_sched_barrier(0);

    float acc[8] = {0.f, 0.f, 0.f, 0.f, 0.f, 0.f, 0.f, 0.f};
    int curRel = 0;
#pragma unroll
    for (int j = 0; j < 32; ++j) {
        if (j < deg) {
            int r_ = (d[j].x >> 16) & 15;
            if (r_ != curRel) {
                GFLUSH();
                curRel = r_;
            }
            float inv_ = __int_as_float(d[j].y);
#pragma unroll
            for (int q = 0; q < 8; ++q)
                acc[q] = fmaf(inv_, bf2f((unsigned short)v[j][q]), acc[q]);
        }
    }
    for (int e = lo + 32; e < hi; ++e) {
        int2 m = sedge[e];
        int r = (m.x >> 16) & 15;
        if (r != curRel) {
            GFLUSH();
            curRel = r;
        }
        float inv = __int_as_float(m.y);
        bf16x8 vv = *(const bf16x8*)(xcol + (size_t)(m.x & 0xFFFF) * HID);
#pragma unroll
        for (int q = 0; q < 8; ++q)
            acc[q] = fmaf(inv, bf2f((unsigned short)vv[q]), acc[q]);
    }
    if (deg > 0) GFLUSH();
}

__global__ __launch_bounds__(256, 2) void fuse2_k(const ushort* __restrict__ X1b,
                                                  const int2* __restrict__ sedge,
                                                  const int* __restrict__ rstart,
                                                  const ushort* __restrict__ WbT2,
                                                  const float* __restrict__ b2,
                                                  float* __restrict__ out) {
    __shared__ bf16x8 Abuf[17 * TILE * 8];  // 69632 B
    __shared__ float P[4 * TILE * NCLS];    // 8192 B
    char* Ab = (char*)Abuf;
    int tid = threadIdx.x;
    int dst0 = blockIdx.x * TILE;

    gather_tile(Ab, X1b, sedge, rstart, dst0, tid);

    int wave = tid >> 6, lane = tid & 63;
    int mr = lane & 15, kq = lane >> 4;
    f32x4 c0 = {0.f, 0.f, 0.f, 0.f}, c1 = {0.f, 0.f, 0.f, 0.f};
    const ushort* wb = WbT2 + mr * HID + kq * 8;
    int sw = (mr & 7) << 4;
    int a00o = ((mr << 7) + (kq << 4)) ^ sw;
    int a01o = ((mr << 7) + 64 + (kq << 4)) ^ sw;
    int a10o = (((16 + mr) << 7) + (kq << 4)) ^ sw;
    int a11o = (((16 + mr) << 7) + 64 + (kq << 4)) ^ sw;

    bf16x8 bk0 = *(const bf16x8*)(wb + wave * 1024);
    bf16x8 bk1 = *(const bf16x8*)(wb + wave * 1024 + 32);
    __syncthreads();

    for (int t = wave; t < 17; t += 4) {
        bf16x8 nb0 = bk0, nb1 = bk1;
        if (t + 4 < 17) {
            nb0 = *(const bf16x8*)(wb + (t + 4) * 1024);
            nb1 = *(const bf16x8*)(wb + (t + 4) * 1024 + 32);
        }
        const char* At = Ab + t * (TILE * 128);
        bf16x8 a00 = *(const bf16x8*)(At + a00o);
        bf16x8 a01 = *(const bf16x8*)(At + a01o);
        bf16x8 a10 = *(const bf16x8*)(At + a10o);
        bf16x8 a11 = *(const bf16x8*)(At + a11o);
        c0 = MFMA16(a00, bk0, c0);
        c0 = MFMA16(a01, bk1, c0);
        c1 = MFMA16(a10, bk0, c1);
        c1 = MFMA16(a11, bk1, c1);
        bk0 = nb0;
        bk1 = nb1;
    }
    float* Pw = P + wave * (TILE * NCLS);
#pragma unroll
    for (int j = 0; j < 4; ++j) {
        Pw[(kq * 4 + j) * NCLS + mr] = c0[j];
        Pw[(16 + kq * 4 + j) * NCLS + mr] = c1[j];
    }
    __syncthreads();

    int idx = tid * 2;
    int row = idx >> 4, c = idx & 15;
    float s0 = P[idx] + P[512 + idx] + P[1024 + idx] + P[1536 + idx] + b2[c];
    float s1 = P[idx + 1] + P[512 + idx + 1] + P[1024 + idx + 1] +
               P[1536 + idx + 1] + b2[c + 1];
    if (dst0 + row < N_NODES) {
        float2 o = make_float2(s0, s1);
        *(float2*)(out + (size_t)(dst0 + row) * NCLS + c) = o;
    }
}

extern "C" void kernel_launch(void* const* d_in, const int* in_sizes, int n_in,
                              void* d_out, int out_size, void* d_ws, size_t ws_size,
                              hipStream_t stream) {
    const int* ei    = (const int*)d_in[0];
    const int* et    = (const int*)d_in[1];
    const float* x   = (const float*)d_in[2];
    const float* W1  = (const float*)d_in[3];
    const float* r1  = (const float*)d_in[4];
    const float* b1  = (const float*)d_in[5];
    const float* W2  = (const float*)d_in[6];
    const float* r2  = (const float*)d_in[7];
    const float* b2  = (const float*)d_in[8];
    float* out = (float*)d_out;

    int E = in_sizes[0] / 2;
    const int* srcp = ei;
    const int* dstp = ei + E;

    int*    bcnt   = (int*)d_ws;                // doubles as rstart after scan
    int*    rank   = bcnt + (NBKT + 20);
    int*    bsum   = rank + E;                  // 512 ints (NSB=391 used)
    int2*   sedge  = (int2*)(bsum + 512);
    ushort* WbT1   = (ushort*)(sedge + E);
    ushort* WbT2   = WbT1 + W1N;
    ushort* xb     = WbT2 + W2N;
    ushort* X1b    = xb + (size_t)N_NODES * HID;
    int*    rstart = bcnt;                      // alias (in-place scan)

    int eb = (E + 255) / 256;
    int cvtThreads = XCHUNKS + W1N + W2N;
    int cvtBlocks = (cvtThreads + 255) / 256;

    // single cooperative pre-kernel (zero + hist/rank + cvt + scans + scat)
    void* kargs[] = {(void*)&srcp, (void*)&dstp, (void*)&et,
                     (void*)&bcnt, (void*)&rank, (void*)&E,
                     (void*)&x, (void*)&W1, (void*)&r1, (void*)&W2, (void*)&r2,
                     (void*)&xb, (void*)&WbT1, (void*)&WbT2,
                     (void*)&bsum, (void*)&sedge};
    hipError_t cerr = hipLaunchCooperativeKernel(
        reinterpret_cast<const void*>(&coop_pre_k), dim3(COOPG), dim3(256),
        kargs, 0u, stream);
    if (cerr != hipSuccess) {
        // fallback: R6-proven 5-kernel chain
        hipMemsetAsync(bcnt, 0, (NBKT + 20) * sizeof(int), stream);
        pre_k<<<eb + cvtBlocks, 256, 0, stream>>>(dstp, et, bcnt, rank, E,
                                                  x, W1, r1, W2, r2, xb, WbT1, WbT2);
        scan1_k<<<NSB, 256, 0, stream>>>(bcnt, bsum);
        scan2_k<<<1, 512, 0, stream>>>(bsum, rstart, E);
        scan3_k<<<NSB, 256, 0, stream>>>(bcnt, bsum);
        scat_k<<<eb, 256, 0, stream>>>(srcp, dstp, et, rank, rstart, sedge, E);
    }

    fuse1_k<<<PGRID, 512, 0, stream>>>(xb, sedge, rstart, WbT1, b1, X1b);
    fuse2_k<<<NTB, 256, 0, stream>>>(X1b, sedge, rstart, WbT2, b2, out);
}

// Round 14
// 236.324 us; speedup vs baseline: 2.7242x; 2.7242x over previous
//
#include <hip/hip_runtime.h>
#include <hip/hip_bf16.h>

#define N_NODES 50000
#define NREL 16
#define HID 64
#define NCLS 16
#define NBKT (N_NODES * NREL)       // 800000 buckets (dst*16 + rel)
#define SB 2048                     // scan elems per block
#define NSB ((NBKT + SB - 1) / SB)  // 391
#define TILE 32                     // dst nodes per tile
#define NTB ((N_NODES + TILE - 1) / TILE)  // 1563
#define PGRID 256                   // persistent blocks for fuse1 (1/CU)
#define XCHUNKS (N_NODES * HID / 8)        // 400000
#define W1N (17 * HID * HID)               // 69632
#define W2N (17 * NCLS * HID)              // 17408

typedef __attribute__((ext_vector_type(8))) short bf16x8;
typedef __attribute__((ext_vector_type(4))) float f32x4;
typedef __attribute__((ext_vector_type(2))) int i32x2;

static __device__ __forceinline__ unsigned short f2bf(float f) {
    __hip_bfloat16 h = __float2bfloat16(f);
    return *reinterpret_cast<unsigned short*>(&h);
}
static __device__ __forceinline__ float bf2f(unsigned short u) {
    __hip_bfloat16 h;
    *reinterpret_cast<unsigned short*>(&h) = u;
    return __bfloat162float(h);
}

#define MFMA16(A, B, C) __builtin_amdgcn_mfma_f32_16x16x32_bf16((A), (B), (C), 0, 0, 0)

// Inline-asm loads: cannot be sunk/split by the compiler; results valid only
// after VWAIT0 (s_waitcnt vmcnt(0) + sched_barrier per rule #18).
#define LD128A(D, P) \
    asm volatile("global_load_dwordx4 %0, %1, off" : "=v"(D) : "v"((const void*)(P)) : "memory")
#define LD64A(D, P) \
    asm volatile("global_load_dwordx2 %0, %1, off" : "=v"(D) : "v"((const void*)(P)) : "memory")
#define VWAIT0()                                           \
    do {                                                   \
        asm volatile("s_waitcnt vmcnt(0)" ::: "memory");   \
        __builtin_amdgcn_sched_barrier(0);                 \
    } while (0)

// ---------------------------------------------------------------------------
// ws layout (R6-proven):
//   bcnt/rstart i32[800020] (zeroed; scan3 -> prefix IN PLACE)
//   | rank i32[E] | bsum i32[512] | sedge int2[E] {src | rel<<16, inv}
//   | WbT1 bf16[17*64*64] [t][n][k] | WbT2 bf16[17*16*64] [t][n][k]
//   | xb bf16[50000*64] | X1b bf16[50000*64]
// Composition of proven-best parts:
//   pre  = R6's rank-based 5-kernel chain (best pre measured; coop-fused
//          variant was 4x slower — grid.sync L2-flushes on gfx950).
//   fuse1 = R10's persistent double-buffered asm-pipelined kernel (56.5 us).
//   fuse2 = R6's 256-thread kernel.
// ---------------------------------------------------------------------------

// K0: merged rank (bucket count + per-edge rank) and cvt
__global__ __launch_bounds__(256) void pre_k(const int* __restrict__ dstp,
                                             const int* __restrict__ et,
                                             int* __restrict__ bcnt,
                                             int* __restrict__ rank, int E,
                                             const float* __restrict__ x,
                                             const float* __restrict__ W1,
                                             const float* __restrict__ root1,
                                             const float* __restrict__ W2,
                                             const float* __restrict__ root2,
                                             ushort* __restrict__ xb,
                                             ushort* __restrict__ WbT1,
                                             ushort* __restrict__ WbT2) {
    int eb = (E + 255) >> 8;
    if ((int)blockIdx.x < eb) {
        int i = blockIdx.x * 256 + threadIdx.x;
        if (i < E) {
            int b = dstp[i] * NREL + et[i];
            rank[i] = atomicAdd(&bcnt[b], 1);
        }
        return;
    }
    int i = (blockIdx.x - eb) * 256 + threadIdx.x;
    if (i < XCHUNKS) {
        float4 f0 = *(const float4*)(x + (size_t)i * 8);
        float4 f1 = *(const float4*)(x + (size_t)i * 8 + 4);
        bf16x8 o;
        o[0] = (short)f2bf(f0.x); o[1] = (short)f2bf(f0.y);
        o[2] = (short)f2bf(f0.z); o[3] = (short)f2bf(f0.w);
        o[4] = (short)f2bf(f1.x); o[5] = (short)f2bf(f1.y);
        o[6] = (short)f2bf(f1.z); o[7] = (short)f2bf(f1.w);
        *(bf16x8*)(xb + (size_t)i * 8) = o;
    } else {
        int j = i - XCHUNKS;
        if (j < W1N) {
            int t = j >> 12, rem = j & 4095, n = rem >> 6, k = rem & 63;
            float v = (t < 16) ? W1[(size_t)t * HID * HID + k * HID + n]
                               : root1[k * HID + n];
            WbT1[j] = f2bf(v);
        } else {
            int m = j - W1N;
            if (m < W2N) {
                int t = m >> 10, rem = m & 1023, n = rem >> 6, k = rem & 63;
                float v = (t < 16) ? W2[(size_t)t * HID * NCLS + k * NCLS + n]
                                   : root2[k * NCLS + n];
                WbT2[m] = f2bf(v);
            }
        }
    }
}

__global__ __launch_bounds__(256) void scan1_k(const int* __restrict__ bcnt,
                                               int* __restrict__ bsum) {
    int b = blockIdx.x, t = threadIdx.x;
    int base = b * SB + t * 8;
    int s = 0;
#pragma unroll
    for (int j = 0; j < 8; ++j)
        if (base + j < NBKT) s += bcnt[base + j];
#pragma unroll
    for (int off = 1; off < 64; off <<= 1) s += __shfl_xor(s, off, 64);
    __shared__ int ws[4];
    if ((t & 63) == 0) ws[t >> 6] = s;
    __syncthreads();
    if (t == 0) bsum[b] = ws[0] + ws[1] + ws[2] + ws[3];
}

__global__ __launch_bounds__(512) void scan2_k(int* __restrict__ bsum,
                                               int* __restrict__ rstart, int E) {
    __shared__ int ts[512];
    int t = threadIdx.x;
    int v = (t < NSB) ? bsum[t] : 0;
    ts[t] = v;
    __syncthreads();
    int acc = v;
    for (int off = 1; off < 512; off <<= 1) {
        int u = (t >= off) ? ts[t - off] : 0;
        __syncthreads();
        acc += u;
        ts[t] = acc;
        __syncthreads();
    }
    if (t < NSB) bsum[t] = acc - v;
    if (t == 0) rstart[NBKT] = E;
}

__global__ __launch_bounds__(256) void scan3_k(int* __restrict__ bcnt,
                                               const int* __restrict__ bsum) {
    int b = blockIdx.x, t = threadIdx.x;
    int base = b * SB + t * 8;
    int a[8];
    int s = 0;
#pragma unroll
    for (int j = 0; j < 8; ++j) {
        a[j] = (base + j < NBKT) ? bcnt[base + j] : 0;
        s += a[j];
    }
    __shared__ int ts[256];
    ts[t] = s;
    __syncthreads();
    int acc = s;
    for (int off = 1; off < 256; off <<= 1) {
        int u = (t >= off) ? ts[t - off] : 0;
        __syncthreads();
        acc += u;
        ts[t] = acc;
        __syncthreads();
    }
    int run = bsum[b] + (acc - s);
#pragma unroll
    for (int j = 0; j < 8; ++j) {
        if (base + j < NBKT) bcnt[base + j] = run;
        run += a[j];
    }
}

// K3: atomic-free scatter; int2 {src | rel<<16, 1/cnt}
__global__ __launch_bounds__(256) void scat_k(const int* __restrict__ srcp,
                                              const int* __restrict__ dstp,
                                              const int* __restrict__ et,
                                              const int* __restrict__ rank,
                                              const int* __restrict__ rstart,
                                              int2* __restrict__ sedge, int E) {
    int i = blockIdx.x * 256 + threadIdx.x;
    if (i < E) {
        int r = et[i];
        int b = dstp[i] * NREL + r;
        int lo = rstart[b], hi = rstart[b + 1];
        float inv = 1.0f / (float)(hi - lo);
        sedge[lo + rank[i]] = make_int2(srcp[i] | (r << 16), __float_as_int(inv));
    }
}

// ---------------------------------------------------------------------------
// fuse1 gather building blocks (R10): 64 groups = 32 nodes x 2 rel-halves.
// Ab row layout: [16 rel][32 node][128 B], XOR-swizzled byte^=((node&7)<<4).
// ---------------------------------------------------------------------------

#define RSTART_LOAD(T, LO, HI)                                                \
    do {                                                                      \
        int node_ = (T) * TILE + g;                                           \
        LO = 0; HI = 0;                                                       \
        if (node_ < N_NODES) {                                                \
            int b0_ = node_ * NREL + h * 8;                                   \
            LO = rstart[b0_];                                                 \
            HI = rstart[b0_ + 8];                                             \
        }                                                                     \
    } while (0)

#define DESC_ISSUE(LO, HI)                                                    \
    do {                                                                      \
        int dg_ = (HI) - (LO);                                                \
        int bs_ = dg_ > 0 ? (LO) : 0;                                         \
        int lt_ = dg_ > 0 ? (HI)-1 : 0;                                       \
        _Pragma("unroll") for (int j_ = 0; j_ < 16; ++j_) {                   \
            int ix_ = bs_ + j_;                                               \
            if (ix_ > lt_) ix_ = lt_;                                         \
            LD64A(d[j_], sedge + ix_);                                        \
        }                                                                     \
    } while (0)

#define FEAT_ISSUE()                                                          \
    do {                                                                      \
        _Pragma("unroll") for (int j_ = 0; j_ < 16; ++j_)                     \
            LD128A(v[j_], xcol + (size_t)(d[j_].x & 0xFFFF) * HID);           \
    } while (0)

#define GFLUSHX(ABP)                                                          \
    {                                                                         \
        bf16x8 o_;                                                            \
        o_[0] = (short)f2bf(acc_[0]); o_[1] = (short)f2bf(acc_[1]);           \
        o_[2] = (short)f2bf(acc_[2]); o_[3] = (short)f2bf(acc_[3]);           \
        o_[4] = (short)f2bf(acc_[4]); o_[5] = (short)f2bf(acc_[5]);           \
        o_[6] = (short)f2bf(acc_[6]); o_[7] = (short)f2bf(acc_[7]);           \
        *(bf16x8*)((ABP) + ((curRel_ * (TILE * 128) + rowoff) ^ swg)) = o_;   \
        acc_[0] = 0.f; acc_[1] = 0.f; acc_[2] = 0.f; acc_[3] = 0.f;           \
        acc_[4] = 0.f; acc_[5] = 0.f; acc_[6] = 0.f; acc_[7] = 0.f;           \
    }

#define CONSUME(ABP, LO, HI)                                                  \
    do {                                                                      \
        char* abp_ = (char*)(ABP);                                            \
        int deg_ = (HI) - (LO);                                               \
        const bf16x8 zz_ = {0, 0, 0, 0, 0, 0, 0, 0};                          \
        _Pragma("unroll") for (int r_ = 0; r_ < 8; ++r_)                      \
            *(bf16x8*)(abp_ + (((h * 8 + r_) * (TILE * 128) + rowoff) ^ swg)) = zz_; \
        float acc_[8] = {0.f, 0.f, 0.f, 0.f, 0.f, 0.f, 0.f, 0.f};             \
        int curRel_ = h * 8;                                                  \
        _Pragma("unroll") for (int j_ = 0; j_ < 16; ++j_) {                   \
            if (j_ < deg_) {                                                  \
                int rr_ = (d[j_].x >> 16) & 15;                               \
                if (rr_ != curRel_) { GFLUSHX(abp_); curRel_ = rr_; }         \
                float iv_ = __int_as_float(d[j_].y);                          \
                _Pragma("unroll") for (int q_ = 0; q_ < 8; ++q_)              \
                    acc_[q_] = fmaf(iv_, bf2f((unsigned short)v[j_][q_]), acc_[q_]); \
            }                                                                 \
        }                                                                     \
        for (int e_ = (LO) + 16; e_ < (HI); ++e_) { /* rare tail */           \
            int2 m_ = sedge[e_];                                              \
            int rr_ = (m_.x >> 16) & 15;                                      \
            if (rr_ != curRel_) { GFLUSHX(abp_); curRel_ = rr_; }             \
            float iv_ = __int_as_float(m_.y);                                 \
            bf16x8 vv_ = *(const bf16x8*)(xcol + (size_t)(m_.x & 0xFFFF) * HID); \
            _Pragma("unroll") for (int q_ = 0; q_ < 8; ++q_)                  \
                acc_[q_] = fmaf(iv_, bf2f((unsigned short)vv_[q_]), acc_[q_]); \
        }                                                                     \
        if (deg_ > 0) GFLUSHX(abp_);                                          \
    } while (0)

__global__ __launch_bounds__(512, 2) void fuse1_k(const ushort* __restrict__ xb,
                                                  const int2* __restrict__ sedge,
                                                  const int* __restrict__ rstart,
                                                  const ushort* __restrict__ WbT1,
                                                  const float* __restrict__ b1,
                                                  ushort* __restrict__ X1b) {
    __shared__ bf16x8 Abuf[2][NREL * TILE * 8];  // 131072 B
    __shared__ float P[4][TILE][16];             // 8192 B
    int tid = threadIdx.x, bid = blockIdx.x;
    int wave = tid >> 6, lane = tid & 63;
    int mr = lane & 15, kq = lane >> 4;
    int cg_ = wave & 3, th = wave >> 2;  // col-group, task-half
    int grp = tid >> 3, l8 = tid & 7;
    int g = grp & 31, h = grp >> 5;
    int swg = (g & 7) << 4;
    int rowoff = (g << 7) + (l8 << 4);
    const ushort* xcol = xb + l8 * 8;
    int sw = (mr & 7) << 4;
    int a00o = ((mr << 7) + (kq << 4)) ^ sw;
    int a01o = ((mr << 7) + 64 + (kq << 4)) ^ sw;
    int a10o = (((16 + mr) << 7) + (kq << 4)) ^ sw;
    int a11o = (((16 + mr) << 7) + 64 + (kq << 4)) ^ sw;

    // weights in registers: this wave's 8 tasks (th*8+i) + root (t=16)
    const ushort* wbase = WbT1 + (cg_ * 16 + mr) * HID + kq * 8;
    bf16x8 w0[8], w1[8];
#pragma unroll
    for (int i = 0; i < 8; ++i) {
        w0[i] = *(const bf16x8*)(wbase + (th * 8 + i) * 4096);
        w1[i] = *(const bf16x8*)(wbase + (th * 8 + i) * 4096 + 32);
    }
    bf16x8 wr0 = *(const bf16x8*)(wbase + 16 * 4096);
    bf16x8 wr1 = *(const bf16x8*)(wbase + 16 * 4096 + 32);
    float4 bv = *(const float4*)(b1 + ((tid * 4) & 63));

    i32x2 d[16];
    bf16x8 v[16];

    // prologue: gather tile `bid` into Abuf[0]
    int lo, hi;
    RSTART_LOAD(bid, lo, hi);
    DESC_ISSUE(lo, hi);
    VWAIT0();
    FEAT_ISSUE();
    VWAIT0();
    CONSUME(&Abuf[0][0], lo, hi);
    int cur = 0;

    for (int k = 0;; ++k) {
        int tile = bid + k * PGRID;
        int dst0 = tile * TILE;
        bool hasNext = (tile + PGRID) < NTB;
        int nlo = 0, nhi = 0;
        if (hasNext) RSTART_LOAD(tile + PGRID, nlo, nhi);
        __syncthreads();  // Abuf[cur] visible to all
        if (hasNext) DESC_ISSUE(nlo, nhi);
        // root A-frags for this tile (asm; clamped rows)
        int r0 = dst0 + mr;      if (r0 >= N_NODES) r0 = N_NODES - 1;
        int r1 = dst0 + 16 + mr; if (r1 >= N_NODES) r1 = N_NODES - 1;
        bf16x8 ra00, ra01, ra10, ra11;
        LD128A(ra00, xb + (size_t)r0 * HID + kq * 8);
        LD128A(ra01, xb + (size_t)r0 * HID + kq * 8 + 32);
        LD128A(ra10, xb + (size_t)r1 * HID + kq * 8);
        LD128A(ra11, xb + (size_t)r1 * HID + kq * 8 + 32);

        const char* Abase = (const char*)&Abuf[cur][0] + th * (8 * TILE * 128);
        f32x4 c0 = {0.f, 0.f, 0.f, 0.f}, c1 = {0.f, 0.f, 0.f, 0.f};
#pragma unroll
        for (int i = 0; i < 4; ++i) {  // first half: desc latency hides here
            const char* At = Abase + i * (TILE * 128);
            bf16x8 a00 = *(const bf16x8*)(At + a00o);
            bf16x8 a01 = *(const bf16x8*)(At + a01o);
            bf16x8 a10 = *(const bf16x8*)(At + a10o);
            bf16x8 a11 = *(const bf16x8*)(At + a11o);
            c0 = MFMA16(a00, w0[i], c0);
            c0 = MFMA16(a01, w1[i], c0);
            c1 = MFMA16(a10, w0[i], c1);
            c1 = MFMA16(a11, w1[i], c1);
        }
        VWAIT0();  // desc + root ready
        if (hasNext) FEAT_ISSUE();  // feature latency hides under half 2
#pragma unroll
        for (int i = 4; i < 8; ++i) {
            const char* At = Abase + i * (TILE * 128);
            bf16x8 a00 = *(const bf16x8*)(At + a00o);
            bf16x8 a01 = *(const bf16x8*)(At + a01o);
            bf16x8 a10 = *(const bf16x8*)(At + a10o);
            bf16x8 a11 = *(const bf16x8*)(At + a11o);
            c0 = MFMA16(a00, w0[i], c0);
            c0 = MFMA16(a01, w1[i], c0);
            c1 = MFMA16(a10, w0[i], c1);
            c1 = MFMA16(a11, w1[i], c1);
        }
        if (th) {  // root task
            c0 = MFMA16(ra00, wr0, c0);
            c0 = MFMA16(ra01, wr1, c0);
            c1 = MFMA16(ra10, wr0, c1);
            c1 = MFMA16(ra11, wr1, c1);
        }
        // cross-half reduce in LDS P
        if (th == 0) {
#pragma unroll
            for (int j = 0; j < 4; ++j) {
                P[cg_][kq * 4 + j][mr] = c0[j];
                P[cg_][16 + kq * 4 + j][mr] = c1[j];
            }
        }
        __syncthreads();
        if (th == 1) {
#pragma unroll
            for (int j = 0; j < 4; ++j) {
                P[cg_][kq * 4 + j][mr] += c0[j];
                P[cg_][16 + kq * 4 + j][mr] += c1[j];
            }
        }
        __syncthreads();
        {
            int idx = tid * 4, row = idx >> 6, colb = idx & 63;
            int node = dst0 + row;
            if (node < N_NODES) {
                f32x4 pv = *(const f32x4*)&P[colb >> 4][row][colb & 15];
                ushort4 o;
                o.x = f2bf(fmaxf(pv[0] + bv.x, 0.f));
                o.y = f2bf(fmaxf(pv[1] + bv.y, 0.f));
                o.z = f2bf(fmaxf(pv[2] + bv.z, 0.f));
                o.w = f2bf(fmaxf(pv[3] + bv.w, 0.f));
                *(ushort4*)(X1b + (size_t)node * HID + colb) = o;
            }
        }
        if (!hasNext) break;
        VWAIT0();  // features ready
        CONSUME(&Abuf[cur ^ 1][0], nlo, nhi);
        cur ^= 1;
    }
}

// ---------------------------------------------------------------------------
// fuse2: R6's proven 256-thread kernel (32-deep clamped branchless gather).
// ---------------------------------------------------------------------------

#define GFLUSH()                                                              \
    {                                                                         \
        bf16x8 o_;                                                            \
        o_[0] = (short)f2bf(acc[0]); o_[1] = (short)f2bf(acc[1]);             \
        o_[2] = (short)f2bf(acc[2]); o_[3] = (short)f2bf(acc[3]);             \
        o_[4] = (short)f2bf(acc[4]); o_[5] = (short)f2bf(acc[5]);             \
        o_[6] = (short)f2bf(acc[6]); o_[7] = (short)f2bf(acc[7]);             \
        *(bf16x8*)(Ab + ((curRel * (TILE * 128) + rowoff) ^ sw)) = o_;        \
        acc[0] = 0.f; acc[1] = 0.f; acc[2] = 0.f; acc[3] = 0.f;               \
        acc[4] = 0.f; acc[5] = 0.f; acc[6] = 0.f; acc[7] = 0.f;               \
    }

static __device__ __forceinline__ void gather_tile(char* Ab,
                                                   const ushort* __restrict__ ft,
                                                   const int2* __restrict__ sedge,
                                                   const int* __restrict__ rstart,
                                                   int dst0, int tid) {
    int g = tid >> 3, l8 = tid & 7;
    int node = dst0 + g;
    bool valid = node < N_NODES;

    int lo = 0, hi = 0;
    if (valid) {
        lo = rstart[node * NREL];
        hi = rstart[node * NREL + NREL];
    }
    int deg = hi - lo;
    int base = (deg > 0) ? lo : 0;
    int last = (deg > 0) ? hi - 1 : 0;

    int sw = (g & 7) << 4;
    int rowoff = (g << 7) + (l8 << 4);
    const bf16x8 zz = {0, 0, 0, 0, 0, 0, 0, 0};

    int2 d[32];
#pragma unroll
    for (int j = 0; j < 32; ++j) {
        int idx = base + j;
        if (idx > last) idx = last;
        d[j] = sedge[idx];
    }

#pragma unroll
    for (int t = 0; t < 16; ++t)
        *(bf16x8*)(Ab + ((t * (TILE * 128) + rowoff) ^ sw)) = zz;
    {
        bf16x8 v = zz;
        if (valid) v = *(const bf16x8*)(ft + (size_t)node * HID + l8 * 8);
        *(bf16x8*)(Ab + ((16 * (TILE * 128) + rowoff) ^ sw)) = v;
    }

    const ushort* xcol = ft + l8 * 8;
    bf16x8 v[32];
#pragma unroll
    for (int j = 0; j < 32; ++j)
        v[j] = *(const bf16x8*)(xcol + (size_t)(d[j].x & 0xFFFF) * HID);
    __builtin_amdgcn_sched_barrier(0);

    float acc[8] = {0.f, 0.f, 0.f, 0.f, 0.f, 0.f, 0.f, 0.f};
    int curRel = 0;
#pragma unroll
    for (int j = 0; j < 32; ++j) {
        if (j < deg) {
            int r_ = (d[j].x >> 16) & 15;
            if (r_ != curRel) {
                GFLUSH();
                curRel = r_;
            }
            float inv_ = __int_as_float(d[j].y);
#pragma unroll
            for (int q = 0; q < 8; ++q)
                acc[q] = fmaf(inv_, bf2f((unsigned short)v[j][q]), acc[q]);
        }
    }
    for (int e = lo + 32; e < hi; ++e) {
        int2 m = sedge[e];
        int r = (m.x >> 16) & 15;
        if (r != curRel) {
            GFLUSH();
            curRel = r;
        }
        float inv = __int_as_float(m.y);
        bf16x8 vv = *(const bf16x8*)(xcol + (size_t)(m.x & 0xFFFF) * HID);
#pragma unroll
        for (int q = 0; q < 8; ++q)
            acc[q] = fmaf(inv, bf2f((unsigned short)vv[q]), acc[q]);
    }
    if (deg > 0) GFLUSH();
}

__global__ __launch_bounds__(256, 2) void fuse2_k(const ushort* __restrict__ X1b,
                                                  const int2* __restrict__ sedge,
                                                  const int* __restrict__ rstart,
                                                  const ushort* __restrict__ WbT2,
                                                  const float* __restrict__ b2,
                                                  float* __restrict__ out) {
    __shared__ bf16x8 Abuf[17 * TILE * 8];  // 69632 B
    __shared__ float P[4 * TILE * NCLS];    // 8192 B
    char* Ab = (char*)Abuf;
    int tid = threadIdx.x;
    int dst0 = blockIdx.x * TILE;

    gather_tile(Ab, X1b, sedge, rstart, dst0, tid);

    int wave = tid >> 6, lane = tid & 63;
    int mr = lane & 15, kq = lane >> 4;
    f32x4 c0 = {0.f, 0.f, 0.f, 0.f}, c1 = {0.f, 0.f, 0.f, 0.f};
    const ushort* wb = WbT2 + mr * HID + kq * 8;
    int sw = (mr & 7) << 4;
    int a00o = ((mr << 7) + (kq << 4)) ^ sw;
    int a01o = ((mr << 7) + 64 + (kq << 4)) ^ sw;
    int a10o = (((16 + mr) << 7) + (kq << 4)) ^ sw;
    int a11o = (((16 + mr) << 7) + 64 + (kq << 4)) ^ sw;

    bf16x8 bk0 = *(const bf16x8*)(wb + wave * 1024);
    bf16x8 bk1 = *(const bf16x8*)(wb + wave * 1024 + 32);
    __syncthreads();

    for (int t = wave; t < 17; t += 4) {
        bf16x8 nb0 = bk0, nb1 = bk1;
        if (t + 4 < 17) {
            nb0 = *(const bf16x8*)(wb + (t + 4) * 1024);
            nb1 = *(const bf16x8*)(wb + (t + 4) * 1024 + 32);
        }
        const char* At = Ab + t * (TILE * 128);
        bf16x8 a00 = *(const bf16x8*)(At + a00o);
        bf16x8 a01 = *(const bf16x8*)(At + a01o);
        bf16x8 a10 = *(const bf16x8*)(At + a10o);
        bf16x8 a11 = *(const bf16x8*)(At + a11o);
        c0 = MFMA16(a00, bk0, c0);
        c0 = MFMA16(a01, bk1, c0);
        c1 = MFMA16(a10, bk0, c1);
        c1 = MFMA16(a11, bk1, c1);
        bk0 = nb0;
        bk1 = nb1;
    }
    float* Pw = P + wave * (TILE * NCLS);
#pragma unroll
    for (int j = 0; j < 4; ++j) {
        Pw[(kq * 4 + j) * NCLS + mr] = c0[j];
        Pw[(16 + kq * 4 + j) * NCLS + mr] = c1[j];
    }
    __syncthreads();

    int idx = tid * 2;
    int row = idx >> 4, c = idx & 15;
    float s0 = P[idx] + P[512 + idx] + P[1024 + idx] + P[1536 + idx] + b2[c];
    float s1 = P[idx + 1] + P[512 + idx + 1] + P[1024 + idx + 1] +
               P[1536 + idx + 1] + b2[c + 1];
    if (dst0 + row < N_NODES) {
        float2 o = make_float2(s0, s1);
        *(float2*)(out + (size_t)(dst0 + row) * NCLS + c) = o;
    }
}

extern "C" void kernel_launch(void* const* d_in, const int* in_sizes, int n_in,
                              void* d_out, int out_size, void* d_ws, size_t ws_size,
                              hipStream_t stream) {
    const int* ei    = (const int*)d_in[0];
    const int* et    = (const int*)d_in[1];
    const float* x   = (const float*)d_in[2];
    const float* W1  = (const float*)d_in[3];
    const float* r1  = (const float*)d_in[4];
    const float* b1  = (const float*)d_in[5];
    const float* W2  = (const float*)d_in[6];
    const float* r2  = (const float*)d_in[7];
    const float* b2  = (const float*)d_in[8];
    float* out = (float*)d_out;

    int E = in_sizes[0] / 2;
    const int* srcp = ei;
    const int* dstp = ei + E;

    int*    bcnt  = (int*)d_ws;                 // doubles as rstart after scan3
    int*    rank  = bcnt + (NBKT + 20);
    int*    bsum  = rank + E;                   // 512 ints (NSB=391 used)
    int2*   sedge = (int2*)(bsum + 512);
    ushort* WbT1  = (ushort*)(sedge + E);
    ushort* WbT2  = WbT1 + W1N;
    ushort* xb    = WbT2 + W2N;
    ushort* X1b   = xb + (size_t)N_NODES * HID;
    int*    rstart = bcnt;                      // alias (in-place scan)

    hipMemsetAsync(bcnt, 0, (NBKT + 20) * sizeof(int), stream);

    int eb = (E + 255) / 256;
    int cvtThreads = XCHUNKS + W1N + W2N;
    int cvtBlocks = (cvtThreads + 255) / 256;

    pre_k<<<eb + cvtBlocks, 256, 0, stream>>>(dstp, et, bcnt, rank, E,
                                              x, W1, r1, W2, r2, xb, WbT1, WbT2);
    scan1_k<<<NSB, 256, 0, stream>>>(bcnt, bsum);
    scan2_k<<<1, 512, 0, stream>>>(bsum, rstart, E);
    scan3_k<<<NSB, 256, 0, stream>>>(bcnt, bsum);
    scat_k<<<eb, 256, 0, stream>>>(srcp, dstp, et, rank, rstart, sedge, E);

    fuse1_k<<<PGRID, 512, 0, stream>>>(xb, sedge, rstart, WbT1, b1, X1b);
    fuse2_k<<<NTB, 256, 0, stream>>>(X1b, sedge, rstart, WbT2, b2, out);
}

// Round 15
// 235.785 us; speedup vs baseline: 2.7304x; 1.0023x over previous
//
#include <hip/hip_runtime.h>
#include <hip/hip_bf16.h>

#define N_NODES 50000
#define NREL 16
#define HID 64
#define NCLS 16
#define NBKT (N_NODES * NREL)       // 800000 buckets (dst*16 + rel)
#define SB 2048                     // scan elems per block
#define NSB ((NBKT + SB - 1) / SB)  // 391
#define TILE 32                     // dst nodes per tile
#define NTB ((N_NODES + TILE - 1) / TILE)  // 1563
#define PGRID 256                   // persistent blocks for fuse1 (1/CU)
#define XCHUNKS (N_NODES * HID / 8)        // 400000
#define W1N (17 * HID * HID)               // 69632
#define W2N (17 * NCLS * HID)              // 17408

typedef __attribute__((ext_vector_type(8))) short bf16x8;
typedef __attribute__((ext_vector_type(4))) float f32x4;
typedef __attribute__((ext_vector_type(2))) int i32x2;

static __device__ __forceinline__ unsigned short f2bf(float f) {
    __hip_bfloat16 h = __float2bfloat16(f);
    return *reinterpret_cast<unsigned short*>(&h);
}
static __device__ __forceinline__ float bf2f(unsigned short u) {
    __hip_bfloat16 h;
    *reinterpret_cast<unsigned short*>(&h) = u;
    return __bfloat162float(h);
}

#define MFMA16(A, B, C) __builtin_amdgcn_mfma_f32_16x16x32_bf16((A), (B), (C), 0, 0, 0)

// Inline-asm loads: cannot be sunk/split by the compiler; results valid only
// after VWAIT0 (s_waitcnt vmcnt(0) + sched_barrier per rule #18).
#define LD128A(D, P) \
    asm volatile("global_load_dwordx4 %0, %1, off" : "=v"(D) : "v"((const void*)(P)) : "memory")
#define LD64A(D, P) \
    asm volatile("global_load_dwordx2 %0, %1, off" : "=v"(D) : "v"((const void*)(P)) : "memory")
#define VWAIT0()                                           \
    do {                                                   \
        asm volatile("s_waitcnt vmcnt(0)" ::: "memory");   \
        __builtin_amdgcn_sched_barrier(0);                 \
    } while (0)

// ---------------------------------------------------------------------------
// ws layout (R6-proven):
//   bcnt/rstart i32[800020] (zeroed; scan23 -> prefix IN PLACE)
//   | rank i32[E] | bsum i32[512] | sedge int2[E] {src | rel<<16, inv}
//   | WbT1 bf16[17*64*64] [t][n][k] | WbT2 bf16[17*16*64] [t][n][k]
//   | xb bf16[50000*64] | X1b bf16[50000*64]
// pre  = R6 rank-based chain, scan2+scan3 merged (clean, no cursor).
// fuse1 = R10 persistent asm-pipelined kernel (57 us, frozen, 4x reproduced).
// fuse2 = R6 structure + R10's forced-asm gather loads (the proven fix for
//         the compiler collapsing the 32-deep load cluster at VGPR~88).
// ---------------------------------------------------------------------------

// K0: merged rank (bucket count + per-edge rank) and cvt
__global__ __launch_bounds__(256) void pre_k(const int* __restrict__ dstp,
                                             const int* __restrict__ et,
                                             int* __restrict__ bcnt,
                                             int* __restrict__ rank, int E,
                                             const float* __restrict__ x,
                                             const float* __restrict__ W1,
                                             const float* __restrict__ root1,
                                             const float* __restrict__ W2,
                                             const float* __restrict__ root2,
                                             ushort* __restrict__ xb,
                                             ushort* __restrict__ WbT1,
                                             ushort* __restrict__ WbT2) {
    int eb = (E + 255) >> 8;
    if ((int)blockIdx.x < eb) {
        int i = blockIdx.x * 256 + threadIdx.x;
        if (i < E) {
            int b = dstp[i] * NREL + et[i];
            rank[i] = atomicAdd(&bcnt[b], 1);
        }
        return;
    }
    int i = (blockIdx.x - eb) * 256 + threadIdx.x;
    if (i < XCHUNKS) {
        float4 f0 = *(const float4*)(x + (size_t)i * 8);
        float4 f1 = *(const float4*)(x + (size_t)i * 8 + 4);
        bf16x8 o;
        o[0] = (short)f2bf(f0.x); o[1] = (short)f2bf(f0.y);
        o[2] = (short)f2bf(f0.z); o[3] = (short)f2bf(f0.w);
        o[4] = (short)f2bf(f1.x); o[5] = (short)f2bf(f1.y);
        o[6] = (short)f2bf(f1.z); o[7] = (short)f2bf(f1.w);
        *(bf16x8*)(xb + (size_t)i * 8) = o;
    } else {
        int j = i - XCHUNKS;
        if (j < W1N) {
            int t = j >> 12, rem = j & 4095, n = rem >> 6, k = rem & 63;
            float v = (t < 16) ? W1[(size_t)t * HID * HID + k * HID + n]
                               : root1[k * HID + n];
            WbT1[j] = f2bf(v);
        } else {
            int m = j - W1N;
            if (m < W2N) {
                int t = m >> 10, rem = m & 1023, n = rem >> 6, k = rem & 63;
                float v = (t < 16) ? W2[(size_t)t * HID * NCLS + k * NCLS + n]
                                   : root2[k * NCLS + n];
                WbT2[m] = f2bf(v);
            }
        }
    }
}

// K2a: per-block sums of bcnt (2048 elems / block, 8 per thread)
__global__ __launch_bounds__(256) void scan1_k(const int* __restrict__ bcnt,
                                               int* __restrict__ bsum) {
    int b = blockIdx.x, t = threadIdx.x;
    int base = b * SB + t * 8;
    int s = 0;
#pragma unroll
    for (int j = 0; j < 8; ++j)
        if (base + j < NBKT) s += bcnt[base + j];
#pragma unroll
    for (int off = 1; off < 64; off <<= 1) s += __shfl_xor(s, off, 64);
    __shared__ int ws[4];
    if ((t & 63) == 0) ws[t >> 6] = s;
    __syncthreads();
    if (t == 0) bsum[b] = ws[0] + ws[1] + ws[2] + ws[3];
}

// K2b: merged scan2+scan3 — each block computes its own cross-block prefix
// (sum of bsum[j<b], <=391 elems), then per-block exclusive scan IN PLACE
// (bcnt -> rstart). Also writes rstart[NBKT] = E. (Validated logic from
// R12/R13; cursor write removed.)
__global__ __launch_bounds__(256) void scan23_k(int* __restrict__ bcnt,
                                                const int* __restrict__ bsum,
                                                int E) {
    int b = blockIdx.x, t = threadIdx.x;
    int ps = 0;
    for (int j = t; j < b; j += 256) ps += bsum[j];
#pragma unroll
    for (int off = 1; off < 64; off <<= 1) ps += __shfl_xor(ps, off, 64);
    __shared__ int wps[4];
    __shared__ int prefix;
    if ((t & 63) == 0) wps[t >> 6] = ps;
    __syncthreads();
    if (t == 0) prefix = wps[0] + wps[1] + wps[2] + wps[3];

    int base = b * SB + t * 8;
    int a[8];
    int s = 0;
#pragma unroll
    for (int j = 0; j < 8; ++j) {
        a[j] = (base + j < NBKT) ? bcnt[base + j] : 0;
        s += a[j];
    }
    __shared__ int ts[256];
    ts[t] = s;
    __syncthreads();  // also publishes `prefix`
    int acc = s;
    for (int off = 1; off < 256; off <<= 1) {
        int u = (t >= off) ? ts[t - off] : 0;
        __syncthreads();
        acc += u;
        ts[t] = acc;
        __syncthreads();
    }
    int run = prefix + (acc - s);
#pragma unroll
    for (int j = 0; j < 8; ++j) {
        if (base + j < NBKT) bcnt[base + j] = run;
        run += a[j];
    }
    if (b == 0 && t == 0) bcnt[NBKT] = E;
}

// K3: atomic-free scatter; int2 {src | rel<<16, 1/cnt}
__global__ __launch_bounds__(256) void scat_k(const int* __restrict__ srcp,
                                              const int* __restrict__ dstp,
                                              const int* __restrict__ et,
                                              const int* __restrict__ rank,
                                              const int* __restrict__ rstart,
                                              int2* __restrict__ sedge, int E) {
    int i = blockIdx.x * 256 + threadIdx.x;
    if (i < E) {
        int r = et[i];
        int b = dstp[i] * NREL + r;
        int lo = rstart[b], hi = rstart[b + 1];
        float inv = 1.0f / (float)(hi - lo);
        sedge[lo + rank[i]] = make_int2(srcp[i] | (r << 16), __float_as_int(inv));
    }
}

// ---------------------------------------------------------------------------
// fuse1 gather building blocks (R10): 64 groups = 32 nodes x 2 rel-halves.
// Ab row layout: [16 rel][32 node][128 B], XOR-swizzled byte^=((node&7)<<4).
// ---------------------------------------------------------------------------

#define RSTART_LOAD(T, LO, HI)                                                \
    do {                                                                      \
        int node_ = (T) * TILE + g;                                           \
        LO = 0; HI = 0;                                                       \
        if (node_ < N_NODES) {                                                \
            int b0_ = node_ * NREL + h * 8;                                   \
            LO = rstart[b0_];                                                 \
            HI = rstart[b0_ + 8];                                             \
        }                                                                     \
    } while (0)

#define DESC_ISSUE(LO, HI)                                                    \
    do {                                                                      \
        int dg_ = (HI) - (LO);                                                \
        int bs_ = dg_ > 0 ? (LO) : 0;                                         \
        int lt_ = dg_ > 0 ? (HI)-1 : 0;                                       \
        _Pragma("unroll") for (int j_ = 0; j_ < 16; ++j_) {                   \
            int ix_ = bs_ + j_;                                               \
            if (ix_ > lt_) ix_ = lt_;                                         \
            LD64A(d[j_], sedge + ix_);                                        \
        }                                                                     \
    } while (0)

#define FEAT_ISSUE()                                                          \
    do {                                                                      \
        _Pragma("unroll") for (int j_ = 0; j_ < 16; ++j_)                     \
            LD128A(v[j_], xcol + (size_t)(d[j_].x & 0xFFFF) * HID);           \
    } while (0)

#define GFLUSHX(ABP)                                                          \
    {                                                                         \
        bf16x8 o_;                                                            \
        o_[0] = (short)f2bf(acc_[0]); o_[1] = (short)f2bf(acc_[1]);           \
        o_[2] = (short)f2bf(acc_[2]); o_[3] = (short)f2bf(acc_[3]);           \
        o_[4] = (short)f2bf(acc_[4]); o_[5] = (short)f2bf(acc_[5]);           \
        o_[6] = (short)f2bf(acc_[6]); o_[7] = (short)f2bf(acc_[7]);           \
        *(bf16x8*)((ABP) + ((curRel_ * (TILE * 128) + rowoff) ^ swg)) = o_;   \
        acc_[0] = 0.f; acc_[1] = 0.f; acc_[2] = 0.f; acc_[3] = 0.f;           \
        acc_[4] = 0.f; acc_[5] = 0.f; acc_[6] = 0.f; acc_[7] = 0.f;           \
    }

#define CONSUME(ABP, LO, HI)                                                  \
    do {                                                                      \
        char* abp_ = (char*)(ABP);                                            \
        int deg_ = (HI) - (LO);                                               \
        const bf16x8 zz_ = {0, 0, 0, 0, 0, 0, 0, 0};                          \
        _Pragma("unroll") for (int r_ = 0; r_ < 8; ++r_)                      \
            *(bf16x8*)(abp_ + (((h * 8 + r_) * (TILE * 128) + rowoff) ^ swg)) = zz_; \
        float acc_[8] = {0.f, 0.f, 0.f, 0.f, 0.f, 0.f, 0.f, 0.f};             \
        int curRel_ = h * 8;                                                  \
        _Pragma("unroll") for (int j_ = 0; j_ < 16; ++j_) {                   \
            if (j_ < deg_) {                                                  \
                int rr_ = (d[j_].x >> 16) & 15;                               \
                if (rr_ != curRel_) { GFLUSHX(abp_); curRel_ = rr_; }         \
                float iv_ = __int_as_float(d[j_].y);                          \
                _Pragma("unroll") for (int q_ = 0; q_ < 8; ++q_)              \
                    acc_[q_] = fmaf(iv_, bf2f((unsigned short)v[j_][q_]), acc_[q_]); \
            }                                                                 \
        }                                                                     \
        for (int e_ = (LO) + 16; e_ < (HI); ++e_) { /* rare tail */           \
            int2 m_ = sedge[e_];                                              \
            int rr_ = (m_.x >> 16) & 15;                                      \
            if (rr_ != curRel_) { GFLUSHX(abp_); curRel_ = rr_; }             \
            float iv_ = __int_as_float(m_.y);                                 \
            bf16x8 vv_ = *(const bf16x8*)(xcol + (size_t)(m_.x & 0xFFFF) * HID); \
            _Pragma("unroll") for (int q_ = 0; q_ < 8; ++q_)                  \
                acc_[q_] = fmaf(iv_, bf2f((unsigned short)vv_[q_]), acc_[q_]); \
        }                                                                     \
        if (deg_ > 0) GFLUSHX(abp_);                                          \
    } while (0)

__global__ __launch_bounds__(512, 2) void fuse1_k(const ushort* __restrict__ xb,
                                                  const int2* __restrict__ sedge,
                                                  const int* __restrict__ rstart,
                                                  const ushort* __restrict__ WbT1,
                                                  const float* __restrict__ b1,
                                                  ushort* __restrict__ X1b) {
    __shared__ bf16x8 Abuf[2][NREL * TILE * 8];  // 131072 B
    __shared__ float P[4][TILE][16];             // 8192 B
    int tid = threadIdx.x, bid = blockIdx.x;
    int wave = tid >> 6, lane = tid & 63;
    int mr = lane & 15, kq = lane >> 4;
    int cg_ = wave & 3, th = wave >> 2;  // col-group, task-half
    int grp = tid >> 3, l8 = tid & 7;
    int g = grp & 31, h = grp >> 5;
    int swg = (g & 7) << 4;
    int rowoff = (g << 7) + (l8 << 4);
    const ushort* xcol = xb + l8 * 8;
    int sw = (mr & 7) << 4;
    int a00o = ((mr << 7) + (kq << 4)) ^ sw;
    int a01o = ((mr << 7) + 64 + (kq << 4)) ^ sw;
    int a10o = (((16 + mr) << 7) + (kq << 4)) ^ sw;
    int a11o = (((16 + mr) << 7) + 64 + (kq << 4)) ^ sw;

    // weights in registers: this wave's 8 tasks (th*8+i) + root (t=16)
    const ushort* wbase = WbT1 + (cg_ * 16 + mr) * HID + kq * 8;
    bf16x8 w0[8], w1[8];
#pragma unroll
    for (int i = 0; i < 8; ++i) {
        w0[i] = *(const bf16x8*)(wbase + (th * 8 + i) * 4096);
        w1[i] = *(const bf16x8*)(wbase + (th * 8 + i) * 4096 + 32);
    }
    bf16x8 wr0 = *(const bf16x8*)(wbase + 16 * 4096);
    bf16x8 wr1 = *(const bf16x8*)(wbase + 16 * 4096 + 32);
    float4 bv = *(const float4*)(b1 + ((tid * 4) & 63));

    i32x2 d[16];
    bf16x8 v[16];

    // prologue: gather tile `bid` into Abuf[0]
    int lo, hi;
    RSTART_LOAD(bid, lo, hi);
    DESC_ISSUE(lo, hi);
    VWAIT0();
    FEAT_ISSUE();
    VWAIT0();
    CONSUME(&Abuf[0][0], lo, hi);
    int cur = 0;

    for (int k = 0;; ++k) {
        int tile = bid + k * PGRID;
        int dst0 = tile * TILE;
        bool hasNext = (tile + PGRID) < NTB;
        int nlo = 0, nhi = 0;
        if (hasNext) RSTART_LOAD(tile + PGRID, nlo, nhi);
        __syncthreads();  // Abuf[cur] visible to all
        if (hasNext) DESC_ISSUE(nlo, nhi);
        // root A-frags for this tile (asm; clamped rows)
        int r0 = dst0 + mr;      if (r0 >= N_NODES) r0 = N_NODES - 1;
        int r1 = dst0 + 16 + mr; if (r1 >= N_NODES) r1 = N_NODES - 1;
        bf16x8 ra00, ra01, ra10, ra11;
        LD128A(ra00, xb + (size_t)r0 * HID + kq * 8);
        LD128A(ra01, xb + (size_t)r0 * HID + kq * 8 + 32);
        LD128A(ra10, xb + (size_t)r1 * HID + kq * 8);
        LD128A(ra11, xb + (size_t)r1 * HID + kq * 8 + 32);

        const char* Abase = (const char*)&Abuf[cur][0] + th * (8 * TILE * 128);
        f32x4 c0 = {0.f, 0.f, 0.f, 0.f}, c1 = {0.f, 0.f, 0.f, 0.f};
#pragma unroll
        for (int i = 0; i < 4; ++i) {  // first half: desc latency hides here
            const char* At = Abase + i * (TILE * 128);
            bf16x8 a00 = *(const bf16x8*)(At + a00o);
            bf16x8 a01 = *(const bf16x8*)(At + a01o);
            bf16x8 a10 = *(const bf16x8*)(At + a10o);
            bf16x8 a11 = *(const bf16x8*)(At + a11o);
            c0 = MFMA16(a00, w0[i], c0);
            c0 = MFMA16(a01, w1[i], c0);
            c1 = MFMA16(a10, w0[i], c1);
            c1 = MFMA16(a11, w1[i], c1);
        }
        VWAIT0();  // desc + root ready
        if (hasNext) FEAT_ISSUE();  // feature latency hides under half 2
#pragma unroll
        for (int i = 4; i < 8; ++i) {
            const char* At = Abase + i * (TILE * 128);
            bf16x8 a00 = *(const bf16x8*)(At + a00o);
            bf16x8 a01 = *(const bf16x8*)(At + a01o);
            bf16x8 a10 = *(const bf16x8*)(At + a10o);
            bf16x8 a11 = *(const bf16x8*)(At + a11o);
            c0 = MFMA16(a00, w0[i], c0);
            c0 = MFMA16(a01, w1[i], c0);
            c1 = MFMA16(a10, w0[i], c1);
            c1 = MFMA16(a11, w1[i], c1);
        }
        if (th) {  // root task
            c0 = MFMA16(ra00, wr0, c0);
            c0 = MFMA16(ra01, wr1, c0);
            c1 = MFMA16(ra10, wr0, c1);
            c1 = MFMA16(ra11, wr1, c1);
        }
        // cross-half reduce in LDS P
        if (th == 0) {
#pragma unroll
            for (int j = 0; j < 4; ++j) {
                P[cg_][kq * 4 + j][mr] = c0[j];
                P[cg_][16 + kq * 4 + j][mr] = c1[j];
            }
        }
        __syncthreads();
        if (th == 1) {
#pragma unroll
            for (int j = 0; j < 4; ++j) {
                P[cg_][kq * 4 + j][mr] += c0[j];
                P[cg_][16 + kq * 4 + j][mr] += c1[j];
            }
        }
        __syncthreads();
        {
            int idx = tid * 4, row = idx >> 6, colb = idx & 63;
            int node = dst0 + row;
            if (node < N_NODES) {
                f32x4 pv = *(const f32x4*)&P[colb >> 4][row][colb & 15];
                ushort4 o;
                o.x = f2bf(fmaxf(pv[0] + bv.x, 0.f));
                o.y = f2bf(fmaxf(pv[1] + bv.y, 0.f));
                o.z = f2bf(fmaxf(pv[2] + bv.z, 0.f));
                o.w = f2bf(fmaxf(pv[3] + bv.w, 0.f));
                *(ushort4*)(X1b + (size_t)node * HID + colb) = o;
            }
        }
        if (!hasNext) break;
        VWAIT0();  // features ready
        CONSUME(&Abuf[cur ^ 1][0], nlo, nhi);
        cur ^= 1;
    }
}

// ---------------------------------------------------------------------------
// fuse2: R6 structure, gather loads FORCED via inline asm (R10's proven fix
// for the collapsed 32-deep cluster): 32 LD64A desc -> wait -> 32 LD128A
// features -> wait -> consume. Only 2 exposed round-trips per block.
// ---------------------------------------------------------------------------

#define GFLUSH()                                                              \
    {                                                                         \
        bf16x8 o_;                                                            \
        o_[0] = (short)f2bf(acc[0]); o_[1] = (short)f2bf(acc[1]);             \
        o_[2] = (short)f2bf(acc[2]); o_[3] = (short)f2bf(acc[3]);             \
        o_[4] = (short)f2bf(acc[4]); o_[5] = (short)f2bf(acc[5]);             \
        o_[6] = (short)f2bf(acc[6]); o_[7] = (short)f2bf(acc[7]);             \
        *(bf16x8*)(Ab + ((curRel * (TILE * 128) + rowoff) ^ sw)) = o_;        \
        acc[0] = 0.f; acc[1] = 0.f; acc[2] = 0.f; acc[3] = 0.f;               \
        acc[4] = 0.f; acc[5] = 0.f; acc[6] = 0.f; acc[7] = 0.f;               \
    }

static __device__ __forceinline__ void gather_tile(char* Ab,
                                                   const ushort* __restrict__ ft,
                                                   const int2* __restrict__ sedge,
                                                   const int* __restrict__ rstart,
                                                   int dst0, int tid) {
    int g = tid >> 3, l8 = tid & 7;
    int node = dst0 + g;
    bool valid = node < N_NODES;

    int lo = 0, hi = 0;
    if (valid) {
        lo = rstart[node * NREL];
        hi = rstart[node * NREL + NREL];
    }
    int deg = hi - lo;
    int base = (deg > 0) ? lo : 0;
    int last = (deg > 0) ? hi - 1 : 0;

    int sw = (g & 7) << 4;
    int rowoff = (g << 7) + (l8 << 4);
    const bf16x8 zz = {0, 0, 0, 0, 0, 0, 0, 0};

    // 32 clamped descriptor loads, asm-forced into one cluster
    i32x2 d[32];
#pragma unroll
    for (int j = 0; j < 32; ++j) {
        int idx = base + j;
        if (idx > last) idx = last;
        LD64A(d[j], sedge + idx);
    }

    // zero relation rows + root row while descriptors are in flight
#pragma unroll
    for (int t = 0; t < 16; ++t)
        *(bf16x8*)(Ab + ((t * (TILE * 128) + rowoff) ^ sw)) = zz;
    {
        bf16x8 v = zz;
        if (valid) v = *(const bf16x8*)(ft + (size_t)node * HID + l8 * 8);
        *(bf16x8*)(Ab + ((16 * (TILE * 128) + rowoff) ^ sw)) = v;
    }
    VWAIT0();  // descriptors (and root load) ready

    // 32 feature loads, asm-forced into one cluster
    const ushort* xcol = ft + l8 * 8;
    bf16x8 v[32];
#pragma unroll
    for (int j = 0; j < 32; ++j)
        LD128A(v[j], xcol + (size_t)(d[j].x & 0xFFFF) * HID);
    VWAIT0();  // features ready

    float acc[8] = {0.f, 0.f, 0.f, 0.f, 0.f, 0.f, 0.f, 0.f};
    int curRel = 0;
#pragma unroll
    for (int j = 0; j < 32; ++j) {
        if (j < deg) {
            int r_ = (d[j].x >> 16) & 15;
            if (r_ != curRel) {
                GFLUSH();
                curRel = r_;
            }
            float inv_ = __int_as_float(d[j].y);
#pragma unroll
            for (int q = 0; q < 8; ++q)
                acc[q] = fmaf(inv_, bf2f((unsigned short)v[j][q]), acc[q]);
        }
    }
    for (int e = lo + 32; e < hi; ++e) {
        int2 m = sedge[e];
        int r = (m.x >> 16) & 15;
        if (r != curRel) {
            GFLUSH();
            curRel = r;
        }
        float inv = __int_as_float(m.y);
        bf16x8 vv = *(const bf16x8*)(xcol + (size_t)(m.x & 0xFFFF) * HID);
#pragma unroll
        for (int q = 0; q < 8; ++q)
            acc[q] = fmaf(inv, bf2f((unsigned short)vv[q]), acc[q]);
    }
    if (deg > 0) GFLUSH();
}

__global__ __launch_bounds__(256, 2) void fuse2_k(const ushort* __restrict__ X1b,
                                                  const int2* __restrict__ sedge,
                                                  const int* __restrict__ rstart,
                                                  const ushort* __restrict__ WbT2,
                                                  const float* __restrict__ b2,
                                                  float* __restrict__ out) {
    __shared__ bf16x8 Abuf[17 * TILE * 8];  // 69632 B
    __shared__ float P[4 * TILE * NCLS];    // 8192 B
    char* Ab = (char*)Abuf;
    int tid = threadIdx.x;
    int dst0 = blockIdx.x * TILE;

    gather_tile(Ab, X1b, sedge, rstart, dst0, tid);

    int wave = tid >> 6, lane = tid & 63;
    int mr = lane & 15, kq = lane >> 4;
    f32x4 c0 = {0.f, 0.f, 0.f, 0.f}, c1 = {0.f, 0.f, 0.f, 0.f};
    const ushort* wb = WbT2 + mr * HID + kq * 8;
    int sw = (mr & 7) << 4;
    int a00o = ((mr << 7) + (kq << 4)) ^ sw;
    int a01o = ((mr << 7) + 64 + (kq << 4)) ^ sw;
    int a10o = (((16 + mr) << 7) + (kq << 4)) ^ sw;
    int a11o = (((16 + mr) << 7) + 64 + (kq << 4)) ^ sw;

    bf16x8 bk0 = *(const bf16x8*)(wb + wave * 1024);
    bf16x8 bk1 = *(const bf16x8*)(wb + wave * 1024 + 32);
    __syncthreads();

    for (int t = wave; t < 17; t += 4) {
        bf16x8 nb0 = bk0, nb1 = bk1;
        if (t + 4 < 17) {
            nb0 = *(const bf16x8*)(wb + (t + 4) * 1024);
            nb1 = *(const bf16x8*)(wb + (t + 4) * 1024 + 32);
        }
        const char* At = Ab + t * (TILE * 128);
        bf16x8 a00 = *(const bf16x8*)(At + a00o);
        bf16x8 a01 = *(const bf16x8*)(At + a01o);
        bf16x8 a10 = *(const bf16x8*)(At + a10o);
        bf16x8 a11 = *(const bf16x8*)(At + a11o);
        c0 = MFMA16(a00, bk0, c0);
        c0 = MFMA16(a01, bk1, c0);
        c1 = MFMA16(a10, bk0, c1);
        c1 = MFMA16(a11, bk1, c1);
        bk0 = nb0;
        bk1 = nb1;
    }
    float* Pw = P + wave * (TILE * NCLS);
#pragma unroll
    for (int j = 0; j < 4; ++j) {
        Pw[(kq * 4 + j) * NCLS + mr] = c0[j];
        Pw[(16 + kq * 4 + j) * NCLS + mr] = c1[j];
    }
    __syncthreads();

    int idx = tid * 2;
    int row = idx >> 4, c = idx & 15;
    float s0 = P[idx] + P[512 + idx] + P[1024 + idx] + P[1536 + idx] + b2[c];
    float s1 = P[idx + 1] + P[512 + idx + 1] + P[1024 + idx + 1] +
               P[1536 + idx + 1] + b2[c + 1];
    if (dst0 + row < N_NODES) {
        float2 o = make_float2(s0, s1);
        *(float2*)(out + (size_t)(dst0 + row) * NCLS + c) = o;
    }
}

extern "C" void kernel_launch(void* const* d_in, const int* in_sizes, int n_in,
                              void* d_out, int out_size, void* d_ws, size_t ws_size,
                              hipStream_t stream) {
    const int* ei    = (const int*)d_in[0];
    const int* et    = (const int*)d_in[1];
    const float* x   = (const float*)d_in[2];
    const float* W1  = (const float*)d_in[3];
    const float* r1  = (const float*)d_in[4];
    const float* b1  = (const float*)d_in[5];
    const float* W2  = (const float*)d_in[6];
    const float* r2  = (const float*)d_in[7];
    const float* b2  = (const float*)d_in[8];
    float* out = (float*)d_out;

    int E = in_sizes[0] / 2;
    const int* srcp = ei;
    const int* dstp = ei + E;

    int*    bcnt  = (int*)d_ws;                 // doubles as rstart after scan23
    int*    rank  = bcnt + (NBKT + 20);
    int*    bsum  = rank + E;                   // 512 ints (NSB=391 used)
    int2*   sedge = (int2*)(bsum + 512);
    ushort* WbT1  = (ushort*)(sedge + E);
    ushort* WbT2  = WbT1 + W1N;
    ushort* xb    = WbT2 + W2N;
    ushort* X1b   = xb + (size_t)N_NODES * HID;
    int*    rstart = bcnt;                      // alias (in-place scan)

    hipMemsetAsync(bcnt, 0, (NBKT + 20) * sizeof(int), stream);

    int eb = (E + 255) / 256;
    int cvtThreads = XCHUNKS + W1N + W2N;
    int cvtBlocks = (cvtThreads + 255) / 256;

    pre_k<<<eb + cvtBlocks, 256, 0, stream>>>(dstp, et, bcnt, rank, E,
                                              x, W1, r1, W2, r2, xb, WbT1, WbT2);
    scan1_k<<<NSB, 256, 0, stream>>>(bcnt, bsum);
    scan23_k<<<NSB, 256, 0, stream>>>(bcnt, bsum, E);
    scat_k<<<eb, 256, 0, stream>>>(srcp, dstp, et, rank, rstart, sedge, E);

    fuse1_k<<<PGRID, 512, 0, stream>>>(xb, sedge, rstart, WbT1, b1, X1b);
    fuse2_k<<<NTB, 256, 0, stream>>>(X1b, sedge, rstart, WbT2, b2, out);
}